// Round 15
// baseline (119.097 us; speedup 1.0000x reference)
//
#include <hip/hip_runtime.h>

#define T_LEN 16384
#define CIN   64
#define COUT  64
#define KTAPS 127
#define TN    256          // t-tile per block
#define XROWS 384          // staged x rows (span: brow0max+31+192 = 383)
#define XPITCH_B 144       // row pitch in bytes (128 data + 16 pad)
#define WT_KS 4096         // COUT*CIN halfwords per tap slice

typedef __attribute__((ext_vector_type(8)))  __bf16 bf16x8;
typedef __attribute__((ext_vector_type(16))) float  f32x16;
typedef __attribute__((ext_vector_type(4)))  float  float4v;

__device__ inline unsigned short f2bf(float f) {
    unsigned u = __builtin_bit_cast(unsigned, f);
    u += 0x7fffu + ((u >> 16) & 1u);        // round-to-nearest-even
    return (unsigned short)(u >> 16);
}

// Wt: 128 slices (slice 127 = zeros, so tap quadruple {j,j+32,j+64,j+96}
// needs no tail branch at j=31). Slice kp (8KB) in MFMA-fragment order:
//   chunk c: f=c>>6 (=cc*2+m), kg=(c>>5)&1, l31=c&31
//   e=0..7:  bf16(W[m*32+l31][cc*16+kg*8+e][126-kp])
__global__ void wt_transform(const float* __restrict__ W,
                             unsigned short* __restrict__ Wt) {
    int t  = blockIdx.x * 256 + threadIdx.x;    // 128*512 threads
    int kp = t >> 9, c = t & 511;
    uint4 pk = {0, 0, 0, 0};
    if (kp < KTAPS) {
        int f = c >> 6, kg = (c >> 5) & 1, l31 = c & 31;
        int cc = f >> 1, m = f & 1;
        int o = m * 32 + l31, ib = cc * 16 + kg * 8;
        const float* src = W + (o * CIN + ib) * KTAPS + (126 - kp);
        unsigned short tmp[8];
        #pragma unroll
        for (int e = 0; e < 8; ++e)
            tmp[e] = f2bf(src[e * KTAPS]);
        pk.x = (unsigned)tmp[0] | ((unsigned)tmp[1] << 16);
        pk.y = (unsigned)tmp[2] | ((unsigned)tmp[3] << 16);
        pk.z = (unsigned)tmp[4] | ((unsigned)tmp[5] << 16);
        pk.w = (unsigned)tmp[6] | ((unsigned)tmp[7] << 16);
    }
    *(uint4*)(Wt + kp * WT_KS + c * 8) = pk;
}

// 256 threads = 4 waves: (quad = j-half) x (ww = 128-t position), 2 blocks/CU.
// Tap-quadruple fragment sharing: per (j, cc) phase, 7 B fragments feed
// 32 MFMAs (fragment(kp,n+1) == fragment(kp+32,n)) -> 2.3x less LDS traffic.
__global__ __launch_bounds__(256, 2)
void conv_mfma(const float* __restrict__ x,
               const unsigned short* __restrict__ Wt,
               float* __restrict__ y) {
    __shared__ __align__(16) char pool[XROWS * XPITCH_B];   // 55296 B
    unsigned short* xs = (unsigned short*)pool;   // [XROWS][72], 144B pitch

    const int tid = threadIdx.x;          // 0..255
    const int bb  = blockIdx.x >> 6;      // batch
    const int tt  = blockIdx.x & 63;      // t-tile
    const int t0  = tt * TN;

    // ---- stage x window [t0-64, t0+320) transposed into padded rows
    {
        const int cin = tid >> 2;             // 0..63
        const int s   = tid & 3;
        const float* xrow = x + (bb * CIN + cin) * T_LEN;
        for (int j = 0; j < 24; ++j) {
            const int w = 16 * j + 4 * s;
            const int u = t0 - 64 + w;        // global t (16B aligned)
            float4v v;
            if (u >= 0 && u + 4 <= T_LEN) {
                v = *(const float4v*)(xrow + u);
            } else {
                v.x = (u + 0 >= 0 && u + 0 < T_LEN) ? xrow[u + 0] : 0.f;
                v.y = (u + 1 >= 0 && u + 1 < T_LEN) ? xrow[u + 1] : 0.f;
                v.z = (u + 2 >= 0 && u + 2 < T_LEN) ? xrow[u + 2] : 0.f;
                v.w = (u + 3 >= 0 && u + 3 < T_LEN) ? xrow[u + 3] : 0.f;
            }
            #pragma unroll
            for (int e = 0; e < 4; ++e) {
                const int we = w + e;
                const float fv = (e == 0) ? v.x : (e == 1) ? v.y : (e == 2) ? v.z : v.w;
                xs[we * 72 + cin] = f2bf(fv);
            }
        }
    }

    const int lane   = tid & 63;
    const int wv     = tid >> 6;          // 0..3
    const int quad   = wv >> 1;           // j-half owner (0/1)
    const int ww     = wv & 1;            // t-position (0/1)
    const int l31    = lane & 31;
    const int kg     = lane >> 5;
    const int twbase = ww * 128;          // wave's 128-t range
    const int brow0  = twbase + l31 + 1;  // xs row at k'=0
    const int j0     = quad ? 16 : 0;

    f32x16 acc[2][4] = {};                // [m: o-tile][n: t-tile]

    __syncthreads();                      // xs ready (only barrier pre-merge)

    // wave stagger within the block (R10: small but real win)
    for (int z = 0; z < wv; ++z)
        __builtin_amdgcn_s_sleep(2);      // ~128 cyc each

    const char* xsb = (const char*)xs;
    const char* wtb = (const char*)Wt + (unsigned)lane * 16;

    // main loop: 16 j's; per (j, cc): 8 A-loads (L1), 7 B ds_read_b128,
    // 32 MFMA (taps j+32s, s=0..3, all into the same acc).
    for (int j = 0; j < 16; ++j) {
        const int jj = j0 + j;
        const int rb = brow0 + jj;                        // p=0 row
        const char* arow = wtb + jj * 8192;               // tap jj slice
        #pragma unroll
        for (int cc = 0; cc < 4; ++cc) {
            // ---- B: 7 shared fragments, rows rb + 32p
            uint4 F[7];
            const char* xp = xsb + rb * XPITCH_B + ((2 * cc + kg) << 4);
            #pragma unroll
            for (int p = 0; p < 7; ++p)
                F[p] = *(const uint4*)(xp + p * (32 * XPITCH_B));
            // ---- s-half 0: taps jj, jj+32
            {
                uint4 a00 = *(const uint4*)(arow +            (cc * 2 + 0) * 1024);
                uint4 a01 = *(const uint4*)(arow +            (cc * 2 + 1) * 1024);
                uint4 a10 = *(const uint4*)(arow + 262144 +   (cc * 2 + 0) * 1024);
                uint4 a11 = *(const uint4*)(arow + 262144 +   (cc * 2 + 1) * 1024);
                #pragma unroll
                for (int n = 0; n < 4; ++n) {
                    bf16x8 b0 = __builtin_bit_cast(bf16x8, F[n]);
                    acc[0][n] = __builtin_amdgcn_mfma_f32_32x32x16_bf16(
                        __builtin_bit_cast(bf16x8, a00), b0, acc[0][n], 0, 0, 0);
                    acc[1][n] = __builtin_amdgcn_mfma_f32_32x32x16_bf16(
                        __builtin_bit_cast(bf16x8, a01), b0, acc[1][n], 0, 0, 0);
                    bf16x8 b1 = __builtin_bit_cast(bf16x8, F[n + 1]);
                    acc[0][n] = __builtin_amdgcn_mfma_f32_32x32x16_bf16(
                        __builtin_bit_cast(bf16x8, a10), b1, acc[0][n], 0, 0, 0);
                    acc[1][n] = __builtin_amdgcn_mfma_f32_32x32x16_bf16(
                        __builtin_bit_cast(bf16x8, a11), b1, acc[1][n], 0, 0, 0);
                }
            }
            // ---- s-half 1: taps jj+64, jj+96 (jj+96 may be the zero slice)
            {
                uint4 a20 = *(const uint4*)(arow + 524288 +   (cc * 2 + 0) * 1024);
                uint4 a21 = *(const uint4*)(arow + 524288 +   (cc * 2 + 1) * 1024);
                uint4 a30 = *(const uint4*)(arow + 786432 +   (cc * 2 + 0) * 1024);
                uint4 a31 = *(const uint4*)(arow + 786432 +   (cc * 2 + 1) * 1024);
                #pragma unroll
                for (int n = 0; n < 4; ++n) {
                    bf16x8 b2 = __builtin_bit_cast(bf16x8, F[n + 2]);
                    acc[0][n] = __builtin_amdgcn_mfma_f32_32x32x16_bf16(
                        __builtin_bit_cast(bf16x8, a20), b2, acc[0][n], 0, 0, 0);
                    acc[1][n] = __builtin_amdgcn_mfma_f32_32x32x16_bf16(
                        __builtin_bit_cast(bf16x8, a21), b2, acc[1][n], 0, 0, 0);
                    bf16x8 b3 = __builtin_bit_cast(bf16x8, F[n + 3]);
                    acc[0][n] = __builtin_amdgcn_mfma_f32_32x32x16_bf16(
                        __builtin_bit_cast(bf16x8, a30), b3, acc[0][n], 0, 0, 0);
                    acc[1][n] = __builtin_amdgcn_mfma_f32_32x32x16_bf16(
                        __builtin_bit_cast(bf16x8, a31), b3, acc[1][n], 0, 0, 0);
                }
            }
        }
    }

    // ---- merge quad1 partials into quad0 via LDS (xs dead now)
    __syncthreads();
    float* msm = (float*)pool;            // 32KB: plane (n*16+r) x 128 f32
    #pragma unroll
    for (int m = 0; m < 2; ++m) {
        if (quad == 1) {
            #pragma unroll
            for (int n = 0; n < 4; ++n)
                #pragma unroll
                for (int r = 0; r < 16; ++r)
                    msm[(n * 16 + r) * 128 + ww * 64 + lane] = acc[m][n][r];
        }
        __syncthreads();
        if (quad == 0) {
            #pragma unroll
            for (int n = 0; n < 4; ++n)
                #pragma unroll
                for (int r = 0; r < 16; ++r)
                    acc[m][n][r] += msm[(n * 16 + r) * 128 + ww * 64 + lane];
        }
        __syncthreads();
    }

    // ---- epilogue (quad0): D col = l31 -> t, row = (r&3)+8*(r>>2)+4*kg -> o
    if (quad == 0) {
        const int ybase = (bb * COUT) * T_LEN;
        #pragma unroll
        for (int m = 0; m < 2; ++m) {
            #pragma unroll
            for (int n = 0; n < 4; ++n) {
                const int t = t0 + twbase + n * 32 + l31;
                #pragma unroll
                for (int r = 0; r < 16; ++r) {
                    const int o = m * 32 + (r & 3) + 8 * (r >> 2) + 4 * kg;
                    y[ybase + o * T_LEN + t] = acc[m][n][r];
                }
            }
        }
    }
}

extern "C" void kernel_launch(void* const* d_in, const int* in_sizes, int n_in,
                              void* d_out, int out_size, void* d_ws, size_t ws_size,
                              hipStream_t stream) {
    const float* x = (const float*)d_in[0];
    const float* W = (const float*)d_in[1];
    float* yout = (float*)d_out;
    unsigned short* Wt = (unsigned short*)d_ws;   // 128*8KB = 1 MB

    wt_transform<<<(128 * 512) / 256, 256, 0, stream>>>(W, Wt);

    const int grid = 8 * (T_LEN / TN);            // 512 blocks, 2/CU
    conv_mfma<<<grid, 256, 0, stream>>>(x, Wt, yout);
}

// Round 16
// 118.959 us; speedup vs baseline: 1.0012x; 1.0012x over previous
//
#include <hip/hip_runtime.h>

#define T_LEN 16384
#define CIN   64
#define COUT  64
#define KTAPS 127
#define TN    256          // t-tile per block
#define XROWS 384          // staged x rows (span: max row 383)
#define XPITCH_B 144       // row pitch in bytes (128 data + 16 pad)
#define WT_KS 4096         // COUT*CIN halfwords per tap slice

typedef __attribute__((ext_vector_type(8)))  __bf16 bf16x8;
typedef __attribute__((ext_vector_type(16))) float  f32x16;
typedef __attribute__((ext_vector_type(4)))  float  float4v;

__device__ inline unsigned short f2bf(float f) {
    unsigned u = __builtin_bit_cast(unsigned, f);
    u += 0x7fffu + ((u >> 16) & 1u);        // round-to-nearest-even
    return (unsigned short)(u >> 16);
}

// Wt: 128 slices (slice 127 = zeros -> tap quadruple {j,j+32,j+64,j+96}
// needs no tail branch). Slice kp (8KB) in MFMA-fragment order:
//   chunk c: f=c>>6 (=cc*2+m), kg=(c>>5)&1, l31=c&31
//   e=0..7:  bf16(W[m*32+l31][cc*16+kg*8+e][126-kp])
__global__ void wt_transform(const float* __restrict__ W,
                             unsigned short* __restrict__ Wt) {
    int t  = blockIdx.x * 256 + threadIdx.x;    // 128*512 threads
    int kp = t >> 9, c = t & 511;
    uint4 pk = {0, 0, 0, 0};
    if (kp < KTAPS) {
        int f = c >> 6, kg = (c >> 5) & 1, l31 = c & 31;
        int cc = f >> 1, m = f & 1;
        int o = m * 32 + l31, ib = cc * 16 + kg * 8;
        const float* src = W + (o * CIN + ib) * KTAPS + (126 - kp);
        unsigned short tmp[8];
        #pragma unroll
        for (int e = 0; e < 8; ++e)
            tmp[e] = f2bf(src[e * KTAPS]);
        pk.x = (unsigned)tmp[0] | ((unsigned)tmp[1] << 16);
        pk.y = (unsigned)tmp[2] | ((unsigned)tmp[3] << 16);
        pk.z = (unsigned)tmp[4] | ((unsigned)tmp[5] << 16);
        pk.w = (unsigned)tmp[6] | ((unsigned)tmp[7] << 16);
    }
    *(uint4*)(Wt + kp * WT_KS + c * 8) = pk;
}

// 256 threads = 4 waves: (quad = j-half) x (ww = 128-t position), 2 blocks/CU.
// Tap-quadruple fragment sharing (7 B frags / 32 MFMA) + A-prefetch ping-pong
// (issue phase p+1's 8 A-loads before phase p's MFMAs; ~2000 cyc of cover).
__global__ __launch_bounds__(256, 2)
void conv_mfma(const float* __restrict__ x,
               const unsigned short* __restrict__ Wt,
               float* __restrict__ y) {
    __shared__ __align__(16) char pool[XROWS * XPITCH_B];   // 55296 B
    unsigned short* xs = (unsigned short*)pool;   // [XROWS][72], 144B pitch

    const int tid = threadIdx.x;          // 0..255
    const int bb  = blockIdx.x >> 6;      // batch
    const int tt  = blockIdx.x & 63;      // t-tile
    const int t0  = tt * TN;

    // ---- stage x window [t0-64, t0+320) transposed into padded rows
    {
        const int cin = tid >> 2;             // 0..63
        const int s   = tid & 3;
        const float* xrow = x + (bb * CIN + cin) * T_LEN;
        for (int j = 0; j < 24; ++j) {
            const int w = 16 * j + 4 * s;
            const int u = t0 - 64 + w;        // global t (16B aligned)
            float4v v;
            if (u >= 0 && u + 4 <= T_LEN) {
                v = *(const float4v*)(xrow + u);
            } else {
                v.x = (u + 0 >= 0 && u + 0 < T_LEN) ? xrow[u + 0] : 0.f;
                v.y = (u + 1 >= 0 && u + 1 < T_LEN) ? xrow[u + 1] : 0.f;
                v.z = (u + 2 >= 0 && u + 2 < T_LEN) ? xrow[u + 2] : 0.f;
                v.w = (u + 3 >= 0 && u + 3 < T_LEN) ? xrow[u + 3] : 0.f;
            }
            #pragma unroll
            for (int e = 0; e < 4; ++e) {
                const int we = w + e;
                const float fv = (e == 0) ? v.x : (e == 1) ? v.y : (e == 2) ? v.z : v.w;
                xs[we * 72 + cin] = f2bf(fv);
            }
        }
    }

    const int lane   = tid & 63;
    const int wv     = tid >> 6;          // 0..3
    const int quad   = wv >> 1;           // j-half owner (0/1)
    const int ww     = wv & 1;            // t-position (0/1)
    const int l31    = lane & 31;
    const int kg     = lane >> 5;
    const int twbase = ww * 128;          // wave's 128-t range
    const int brow0  = twbase + l31 + 1;  // xs row at k'=0
    const int j0     = quad ? 16 : 0;

    const char* xsb = (const char*)xs;
    const char* wtb = (const char*)Wt + (unsigned)lane * 16;

    f32x16 acc[2][4] = {};                // [m: o-tile][n: t-tile] (AGPRs)
    uint4 aP0, aP1, aP2, aP3, aP4, aP5, aP6, aP7;   // A ping
    uint4 aQ0, aQ1, aQ2, aQ3, aQ4, aQ5, aQ6, aQ7;   // A pong

    // A-chunk (s,m) for tap-quadruple base jj, cin-chunk cc:
    //   wtb + jj*8192 + cc*2048 + s*262144 + m*1024
    #define LOADA8(P, jj, cc)                                               \
        do { const char* p_ = wtb + (unsigned)(jj) * 8192 + (cc) * 2048;    \
            P##0 = *(const uint4*)(p_);                                     \
            P##1 = *(const uint4*)(p_ + 1024);                              \
            P##2 = *(const uint4*)(p_ + 262144);                            \
            P##3 = *(const uint4*)(p_ + 263168);                            \
            P##4 = *(const uint4*)(p_ + 524288);                            \
            P##5 = *(const uint4*)(p_ + 525312);                            \
            P##6 = *(const uint4*)(p_ + 786432);                            \
            P##7 = *(const uint4*)(p_ + 787456); } while (0)

    #define MM1(av, bv, m, n)                                               \
        acc[m][n] = __builtin_amdgcn_mfma_f32_32x32x16_bf16(                \
            __builtin_bit_cast(bf16x8, av), __builtin_bit_cast(bf16x8, bv), \
            acc[m][n], 0, 0, 0)

    // phase: prefetch A(jpf,cpf) into P; ds-load 7 B frags; 32 MFMA with U
    #define PHASE(U, P, jpf, cpf, ccur)                                     \
        do { LOADA8(P, jpf, cpf);                                           \
            uint4 F[7];                                                     \
            { const char* xp_ = xsb + rb * XPITCH_B + ((2*(ccur)+kg) << 4); \
              _Pragma("unroll")                                             \
              for (int q_ = 0; q_ < 7; ++q_)                                \
                  F[q_] = *(const uint4*)(xp_ + q_ * (32 * XPITCH_B)); }    \
            _Pragma("unroll")                                               \
            for (int n_ = 0; n_ < 4; ++n_) {                                \
                MM1(U##0, F[n_],     0, n_); MM1(U##1, F[n_],     1, n_);   \
                MM1(U##2, F[n_ + 1], 0, n_); MM1(U##3, F[n_ + 1], 1, n_);   \
                MM1(U##4, F[n_ + 2], 0, n_); MM1(U##5, F[n_ + 2], 1, n_);   \
                MM1(U##6, F[n_ + 3], 0, n_); MM1(U##7, F[n_ + 3], 1, n_);   \
            } } while (0)

    LOADA8(aP, j0, 0);                    // prologue (overlaps the barrier)
    __syncthreads();                      // xs ready (only barrier pre-merge)

    // wave stagger within the block (R10: small but real win)
    for (int z = 0; z < wv; ++z)
        __builtin_amdgcn_s_sleep(2);      // ~128 cyc each

    // 16 j x 4 cc phases; per phase 8 A (prefetched), 7 B ds_read, 32 MFMA.
    // Last phase of j prefetches (j+1, cc=0); j0+16 <= 32 is a valid slice.
    for (int j = 0; j < 16; ++j) {
        const int jj = j0 + j;
        const int rb = brow0 + jj;
        PHASE(aP, aQ, jj,     1, 0);
        PHASE(aQ, aP, jj,     2, 1);
        PHASE(aP, aQ, jj,     3, 2);
        PHASE(aQ, aP, jj + 1, 0, 3);
    }

    // ---- merge quad1 partials into quad0 via LDS (xs dead now)
    __syncthreads();
    float* msm = (float*)pool;            // 32KB: plane (n*16+r) x 128 f32
    #pragma unroll
    for (int m = 0; m < 2; ++m) {
        if (quad == 1) {
            #pragma unroll
            for (int n = 0; n < 4; ++n)
                #pragma unroll
                for (int r = 0; r < 16; ++r)
                    msm[(n * 16 + r) * 128 + ww * 64 + lane] = acc[m][n][r];
        }
        __syncthreads();
        if (quad == 0) {
            #pragma unroll
            for (int n = 0; n < 4; ++n)
                #pragma unroll
                for (int r = 0; r < 16; ++r)
                    acc[m][n][r] += msm[(n * 16 + r) * 128 + ww * 64 + lane];
        }
        __syncthreads();
    }

    // ---- epilogue (quad0): D col = l31 -> t, row = (r&3)+8*(r>>2)+4*kg -> o
    if (quad == 0) {
        const int ybase = (bb * COUT) * T_LEN;
        #pragma unroll
        for (int m = 0; m < 2; ++m) {
            #pragma unroll
            for (int n = 0; n < 4; ++n) {
                const int t = t0 + twbase + n * 32 + l31;
                #pragma unroll
                for (int r = 0; r < 16; ++r) {
                    const int o = m * 32 + (r & 3) + 8 * (r >> 2) + 4 * kg;
                    y[ybase + o * T_LEN + t] = acc[m][n][r];
                }
            }
        }
    }
}

extern "C" void kernel_launch(void* const* d_in, const int* in_sizes, int n_in,
                              void* d_out, int out_size, void* d_ws, size_t ws_size,
                              hipStream_t stream) {
    const float* x = (const float*)d_in[0];
    const float* W = (const float*)d_in[1];
    float* yout = (float*)d_out;
    unsigned short* Wt = (unsigned short*)d_ws;   // 128*8KB = 1 MB

    wt_transform<<<(128 * 512) / 256, 256, 0, stream>>>(W, Wt);

    const int grid = 8 * (T_LEN / TN);            // 512 blocks, 2/CU
    conv_mfma<<<grid, 256, 0, stream>>>(x, Wt, yout);
}

// Round 17
// 113.599 us; speedup vs baseline: 1.0484x; 1.0472x over previous
//
#include <hip/hip_runtime.h>

#define T_LEN 16384
#define CIN   64
#define COUT  64
#define KTAPS 127
#define TN    256          // t-tile per block
#define XROWS 384          // staged x rows
#define XPITCH_B 144       // row pitch in bytes (128 data + 16 pad)
#define WT_KS 4096         // COUT*CIN halfwords per tap slice

typedef __attribute__((ext_vector_type(8)))  __bf16 bf16x8;
typedef __attribute__((ext_vector_type(16))) float  f32x16;
typedef __attribute__((ext_vector_type(4)))  float  float4v;

__device__ inline unsigned short f2bf(float f) {
    unsigned u = __builtin_bit_cast(unsigned, f);
    u += 0x7fffu + ((u >> 16) & 1u);        // round-to-nearest-even
    return (unsigned short)(u >> 16);
}

// Wt[kp] slice (8KB) in MFMA-fragment order (see R5 derivation):
//   chunk c: f=c>>6 (=cc*2+m), kg=(c>>5)&1, l31=c&31
//   e=0..7:  bf16(W[m*32+l31][cc*16+kg*8+e][126-kp])
__global__ void wt_transform(const float* __restrict__ W,
                             unsigned short* __restrict__ Wt) {
    int t  = blockIdx.x * 256 + threadIdx.x;    // 127*512 threads
    int kp = t >> 9, c = t & 511;
    int f = c >> 6, kg = (c >> 5) & 1, l31 = c & 31;
    int cc = f >> 1, m = f & 1;
    int o = m * 32 + l31, ib = cc * 16 + kg * 8;
    const float* src = W + (o * CIN + ib) * KTAPS + (126 - kp);
    unsigned short tmp[8];
    #pragma unroll
    for (int e = 0; e < 8; ++e)
        tmp[e] = f2bf(src[e * KTAPS]);
    uint4 pk;
    pk.x = (unsigned)tmp[0] | ((unsigned)tmp[1] << 16);
    pk.y = (unsigned)tmp[2] | ((unsigned)tmp[3] << 16);
    pk.z = (unsigned)tmp[4] | ((unsigned)tmp[5] << 16);
    pk.w = (unsigned)tmp[6] | ((unsigned)tmp[7] << 16);
    *(uint4*)(Wt + kp * WT_KS + c * 8) = pk;
}

// 256 threads = 4 waves: (quad = tap-half) x (ww = 128-t position).
// 2 blocks/CU; T19 sched_group_barrier gives a time-homogeneous
// [1 ds_read : 2 MFMA] instruction mix so LDS and MFMA pipes run
// concurrently even when co-resident waves phase-lock.
__global__ __launch_bounds__(256, 2)
void conv_mfma(const float* __restrict__ x,
               const unsigned short* __restrict__ Wt,
               float* __restrict__ y) {
    __shared__ __align__(16) char pool[XROWS * XPITCH_B];   // 55296 B
    unsigned short* xs = (unsigned short*)pool;   // [XROWS][72], 144B pitch

    const int tid = threadIdx.x;          // 0..255
    const int bb  = blockIdx.x >> 6;      // batch
    const int tt  = blockIdx.x & 63;      // t-tile
    const int t0  = tt * TN;

    // ---- stage x window [t0-64, t0+320) transposed into padded rows
    {
        const int cin = tid >> 2;             // 0..63
        const int s   = tid & 3;
        const float* xrow = x + (bb * CIN + cin) * T_LEN;
        for (int j = 0; j < 24; ++j) {
            const int w = 16 * j + 4 * s;
            const int u = t0 - 64 + w;        // global t (16B aligned)
            float4v v;
            if (u >= 0 && u + 4 <= T_LEN) {
                v = *(const float4v*)(xrow + u);
            } else {
                v.x = (u + 0 >= 0 && u + 0 < T_LEN) ? xrow[u + 0] : 0.f;
                v.y = (u + 1 >= 0 && u + 1 < T_LEN) ? xrow[u + 1] : 0.f;
                v.z = (u + 2 >= 0 && u + 2 < T_LEN) ? xrow[u + 2] : 0.f;
                v.w = (u + 3 >= 0 && u + 3 < T_LEN) ? xrow[u + 3] : 0.f;
            }
            #pragma unroll
            for (int e = 0; e < 4; ++e) {
                const int we = w + e;
                const float fv = (e == 0) ? v.x : (e == 1) ? v.y : (e == 2) ? v.z : v.w;
                xs[we * 72 + cin] = f2bf(fv);
            }
        }
    }

    const int lane   = tid & 63;
    const int wv     = tid >> 6;          // 0..3
    const int quad   = wv >> 1;           // tap-half owner (0/1)
    const int ww     = wv & 1;            // t-position (0/1)
    const int l31    = lane & 31;
    const int kg     = lane >> 5;
    const int twbase = ww * 128;          // wave's 128-t range
    const int brow0  = twbase + l31 + 1;  // xs row at k'=0

    const int kp0  = quad ? 64 : 0;
    const int ntap = quad ? 63 : 64;

    // per-lane A-fragment global base: + kp*8192 + f*1024, f = cc*2+m
    const char* ab = (const char*)Wt + lane * 16;

    f32x16 acc[2][4] = {};                // [m: o-tile][n: t-tile]
    uint4 a0r[8], a1r[8];                 // ping-pong A prefetch (cross-tap)
    uint4 bA[4], bB[4];                   // B reg double-buffer (cross-cc)

    #define LOADA(dst, kp)                                                  \
        do { const char* p_ = ab + (kp) * 8192;                             \
            _Pragma("unroll")                                               \
            for (int f = 0; f < 8; ++f)                                     \
                dst[f] = *(const uint4*)(p_ + f * 1024); } while (0)

    // one ds_read_b128 per n: lane's B fragment is contiguous 16B
    #define LOADB(dst, rb, cidx)                                            \
        do { const char* xp_ = (const char*)xs + (rb) * XPITCH_B            \
                               + ((2 * (cidx) + kg) << 4);                  \
            _Pragma("unroll")                                               \
            for (int n = 0; n < 4; ++n)                                     \
                dst[n] = *(const uint4*)(xp_ + n * (32 * XPITCH_B));        \
        } while (0)

    #define MFMAB(bv, ar, cidx)                                             \
        do { bf16x8 a0 = __builtin_bit_cast(bf16x8, ar[(cidx) * 2 + 0]);    \
            bf16x8 a1 = __builtin_bit_cast(bf16x8, ar[(cidx) * 2 + 1]);     \
            _Pragma("unroll")                                               \
            for (int n = 0; n < 4; ++n) {                                   \
                bf16x8 b = __builtin_bit_cast(bf16x8, bv[n]);               \
                acc[0][n] = __builtin_amdgcn_mfma_f32_32x32x16_bf16(a0, b, acc[0][n], 0, 0, 0); \
                acc[1][n] = __builtin_amdgcn_mfma_f32_32x32x16_bf16(a1, b, acc[1][n], 0, 0, 0); \
            } } while (0)

    // T19: pin the emitted order to [1 ds_read, 2 MFMA] x 4 per phase.
    #define SGB_MIX4()                                                      \
        do { _Pragma("unroll")                                              \
            for (int s_ = 0; s_ < 4; ++s_) {                                \
                __builtin_amdgcn_sched_group_barrier(0x100, 1, 0);          \
                __builtin_amdgcn_sched_group_barrier(0x008, 2, 0);          \
            } } while (0)

    #define PHASE(curv, nxtv, ar, cidx, rbn, cn)                            \
        do { LOADB(nxtv, rbn, cn);                                          \
            MFMAB(curv, ar, cidx);                                          \
            SGB_MIX4(); } while (0)

    #define TAP(ar, kp)                                                     \
        do {                                                                \
            PHASE(bA, bB, ar, 0, brow0 + (kp),     1);                      \
            PHASE(bB, bA, ar, 1, brow0 + (kp),     2);                      \
            PHASE(bA, bB, ar, 2, brow0 + (kp),     3);                      \
            PHASE(bB, bA, ar, 3, brow0 + (kp) + 1, 0);                      \
        } while (0)

    LOADA(a0r, kp0);                       // overlaps the barrier
    __syncthreads();                       // xs ready (only barrier pre-merge)

    // wave stagger within the block (blocks decorrelate on their own)
    for (int z = 0; z < wv; ++z)
        __builtin_amdgcn_s_sleep(2);       // ~128 cyc each

    LOADB(bA, brow0 + kp0, 0);             // prime B pipeline

    // barrier-free main loop: waves drift freely over their tap ranges
    for (int i = 0; i < ntap; i += 2) {
        if (i + 1 < ntap) LOADA(a1r, kp0 + i + 1);    // A issue-early
        TAP(a0r, kp0 + i);
        if (i + 2 < ntap) LOADA(a0r, kp0 + i + 2);
        if (i + 1 < ntap) TAP(a1r, kp0 + i + 1);
    }

    // ---- merge quad1 partials into quad0 via LDS (xs dead now)
    __syncthreads();
    float* msm = (float*)pool;            // 32KB: plane (n*16+r) x 128 f32
    #pragma unroll
    for (int m = 0; m < 2; ++m) {
        if (quad == 1) {
            #pragma unroll
            for (int n = 0; n < 4; ++n)
                #pragma unroll
                for (int r = 0; r < 16; ++r)
                    msm[(n * 16 + r) * 128 + ww * 64 + lane] = acc[m][n][r];
        }
        __syncthreads();
        if (quad == 0) {
            #pragma unroll
            for (int n = 0; n < 4; ++n)
                #pragma unroll
                for (int r = 0; r < 16; ++r)
                    acc[m][n][r] += msm[(n * 16 + r) * 128 + ww * 64 + lane];
        }
        __syncthreads();
    }

    // ---- epilogue (quad0): D col = l31 -> t, row = (r&3)+8*(r>>2)+4*kg -> o
    if (quad == 0) {
        const int ybase = (bb * COUT) * T_LEN;
        #pragma unroll
        for (int m = 0; m < 2; ++m) {
            #pragma unroll
            for (int n = 0; n < 4; ++n) {
                const int t = t0 + twbase + n * 32 + l31;
                #pragma unroll
                for (int r = 0; r < 16; ++r) {
                    const int o = m * 32 + (r & 3) + 8 * (r >> 2) + 4 * kg;
                    y[ybase + o * T_LEN + t] = acc[m][n][r];
                }
            }
        }
    }
}

extern "C" void kernel_launch(void* const* d_in, const int* in_sizes, int n_in,
                              void* d_out, int out_size, void* d_ws, size_t ws_size,
                              hipStream_t stream) {
    const float* x = (const float*)d_in[0];
    const float* W = (const float*)d_in[1];
    float* yout = (float*)d_out;
    unsigned short* Wt = (unsigned short*)d_ws;   // 127*4096*2 B ~= 1 MB

    wt_transform<<<(KTAPS * 512) / 256, 256, 0, stream>>>(W, Wt);

    const int grid = 8 * (T_LEN / TN);            // 512 blocks, 2/CU
    conv_mfma<<<grid, 256, 0, stream>>>(x, Wt, yout);
}